// Round 5
// baseline (162.996 us; speedup 1.0000x reference)
//
#include <hip/hip_runtime.h>

// N=8, H=512, W=512, K=8, V=100000, F=200000.
// Outputs flat in d_out (f32): images (npix*4) | coords (npix*24) | normals (npix*24)
//
// R5:
//  - bf16 face table 16B/face (3.2 MB, L2-resident), NT loads on streams [R2/R3]
//  - LDS-staged coalesced stores [R4 win: 242->161us]
//  - NEW: b128 LDS transpose, layout lds4[sub][pix] with row stride 261:
//    writes lane-contiguous (conflict-free ds_write_b128), reads spread over
//    banks via gcd(20,32)=4 stride pattern (~2-way, free). 24 b128 ops vs
//    ~96 scalar ops. Texel load hoisted to overlap gather issue.

#define KF 8
#define ROWSTRIDE 261   // f32x4 slots per 'sub' row; 6*261*16B = 25.06 KB

typedef float f32x4 __attribute__((ext_vector_type(4)));
typedef int   i32x4 __attribute__((ext_vector_type(4)));
typedef unsigned int u32x4 __attribute__((ext_vector_type(4)));

__device__ __forceinline__ unsigned short f2bf(float x) {
    unsigned u = __float_as_uint(x);
    unsigned r = u + 0x7FFFu + ((u >> 16) & 1u);   // round-to-nearest-even
    return (unsigned short)(r >> 16);
}
__device__ __forceinline__ float bf2f(unsigned int hi16) {
    return __uint_as_float(hi16 << 16);
}

// ---------------------------------------------------------------------------
// Kernel 1: bf16 face table, 16 B/face: {cx,cy | cz,nx | ny,nz | 0}
// ---------------------------------------------------------------------------
__global__ void build_face_table_kernel(const float* __restrict__ verts,
                                        const int* __restrict__ faces,
                                        const float* __restrict__ fnorm,
                                        u32x4* __restrict__ table,
                                        int F) {
    int f = blockIdx.x * blockDim.x + threadIdx.x;
    if (f >= F) return;
    int i0 = faces[3 * f + 0];
    int i1 = faces[3 * f + 1];
    int i2 = faces[3 * f + 2];
    const float inv3 = 1.0f / 3.0f;
    float cx = (verts[3 * i0 + 0] + verts[3 * i1 + 0] + verts[3 * i2 + 0]) * inv3;
    float cy = (verts[3 * i0 + 1] + verts[3 * i1 + 1] + verts[3 * i2 + 1]) * inv3;
    float cz = (verts[3 * i0 + 2] + verts[3 * i1 + 2] + verts[3 * i2 + 2]) * inv3;
    float nx = fnorm[3 * f + 0];
    float ny = fnorm[3 * f + 1];
    float nz = fnorm[3 * f + 2];
    u32x4 t;
    t.x = (unsigned)f2bf(cx) | ((unsigned)f2bf(cy) << 16);
    t.y = (unsigned)f2bf(cz) | ((unsigned)f2bf(nx) << 16);
    t.z = (unsigned)f2bf(ny) | ((unsigned)f2bf(nz) << 16);
    t.w = 0u;
    table[f] = t;
}

// ---------------------------------------------------------------------------
// Kernel 2 (fast path, npix % 256 == 0): b128 LDS transpose + coalesced stores
// ---------------------------------------------------------------------------
__global__ void __launch_bounds__(256) shade_lds_kernel(
    const int* __restrict__ p2f,
    const float* __restrict__ texels,
    const u32x4* __restrict__ table,
    f32x4* __restrict__ images,    // npix
    f32x4* __restrict__ coords,    // npix*6
    f32x4* __restrict__ normals,   // npix*6
    int npix) {
    __shared__ f32x4 lds4[6 * ROWSTRIDE];
    const int tid = threadIdx.x;
    const int p = blockIdx.x * 256 + tid;   // grid sized so p < npix

    const i32x4* pf = (const i32x4*)(p2f + (size_t)p * KF);
    i32x4 fa = __builtin_nontemporal_load(&pf[0]);
    i32x4 fb = __builtin_nontemporal_load(&pf[1]);
    int fid[KF] = {fa.x, fa.y, fa.z, fa.w, fb.x, fb.y, fb.z, fb.w};

    // hoist texel load: issue early so it's in flight during the gathers
    bool fg = fa.x >= 0;
    f32x4 tex;
    if (fg) tex = __builtin_nontemporal_load((const f32x4*)(texels + (size_t)p * (KF * 3)));

    float c[24], n[24];
#pragma unroll
    for (int k = 0; k < KF; ++k) {
        int f = fid[k];
        int fs = f < 0 ? 0 : f;                  // predicated safe index
        u32x4 t = table[fs];                     // cached gather (L2-resident)
        bool live = f >= 0;
        c[3 * k + 0] = live ? bf2f(t.x & 0xFFFFu) : 0.0f;
        c[3 * k + 1] = live ? bf2f(t.x >> 16)     : 0.0f;
        c[3 * k + 2] = live ? bf2f(t.y & 0xFFFFu) : 0.0f;
        n[3 * k + 0] = live ? bf2f(t.y >> 16)     : 0.0f;
        n[3 * k + 1] = live ? bf2f(t.z & 0xFFFFu) : 0.0f;
        n[3 * k + 2] = live ? bf2f(t.z >> 16)     : 0.0f;
    }

    const size_t gbase = (size_t)blockIdx.x * (256 * 6);   // block's f32x4 base

    // ---- pass 1: coords ----
#pragma unroll
    for (int q = 0; q < 6; ++q) {
        f32x4 v = {c[4 * q + 0], c[4 * q + 1], c[4 * q + 2], c[4 * q + 3]};
        lds4[q * ROWSTRIDE + tid] = v;          // lane-contiguous b128 write
    }

    // images store in the barrier shadow
    f32x4 img;
    if (fg) { img.x = tex.x; img.y = tex.y; img.z = tex.z; img.w = 1.0f; }
    else    { img.x = 1.0f;  img.y = 1.0f;  img.z = 1.0f;  img.w = 0.0f; }
    images[p] = img;

    __syncthreads();
#pragma unroll
    for (int j = 0; j < 6; ++j) {
        int idx = tid + 256 * j;                // 0..1535 lane-consecutive
        int pix = idx / 6;
        int sub = idx - pix * 6;
        coords[gbase + idx] = lds4[sub * ROWSTRIDE + pix];   // b128 read + coalesced store
    }
    __syncthreads();

    // ---- pass 2: normals ----
#pragma unroll
    for (int q = 0; q < 6; ++q) {
        f32x4 v = {n[4 * q + 0], n[4 * q + 1], n[4 * q + 2], n[4 * q + 3]};
        lds4[q * ROWSTRIDE + tid] = v;
    }
    __syncthreads();
#pragma unroll
    for (int j = 0; j < 6; ++j) {
        int idx = tid + 256 * j;
        int pix = idx / 6;
        int sub = idx - pix * 6;
        normals[gbase + idx] = lds4[sub * ROWSTRIDE + pix];
    }
}

// ---------------------------------------------------------------------------
// Fallback (ws too small or npix % 256 != 0): inline gather, direct stores.
// ---------------------------------------------------------------------------
__global__ void __launch_bounds__(256) shade_inline_kernel(
    const int* __restrict__ p2f,
    const float* __restrict__ texels,
    const float* __restrict__ verts,
    const int* __restrict__ faces,
    const float* __restrict__ fnorm,
    f32x4* __restrict__ images,
    f32x4* __restrict__ coords,
    f32x4* __restrict__ normals,
    int npix) {
    int p = blockIdx.x * blockDim.x + threadIdx.x;
    if (p >= npix) return;

    const i32x4* pf = (const i32x4*)(p2f + (size_t)p * KF);
    i32x4 fa = pf[0];
    i32x4 fb = pf[1];
    int fid[KF] = {fa.x, fa.y, fa.z, fa.w, fb.x, fb.y, fb.z, fb.w};

    float c[24], n[24];
#pragma unroll
    for (int k = 0; k < KF; ++k) {
        int f = fid[k];
        float cx = 0.f, cy = 0.f, cz = 0.f, nx = 0.f, ny = 0.f, nz = 0.f;
        if (f >= 0) {
            int i0 = faces[3 * f + 0];
            int i1 = faces[3 * f + 1];
            int i2 = faces[3 * f + 2];
            const float inv3 = 1.0f / 3.0f;
            cx = (verts[3 * i0 + 0] + verts[3 * i1 + 0] + verts[3 * i2 + 0]) * inv3;
            cy = (verts[3 * i0 + 1] + verts[3 * i1 + 1] + verts[3 * i2 + 1]) * inv3;
            cz = (verts[3 * i0 + 2] + verts[3 * i1 + 2] + verts[3 * i2 + 2]) * inv3;
            nx = fnorm[3 * f + 0];
            ny = fnorm[3 * f + 1];
            nz = fnorm[3 * f + 2];
        }
        c[3 * k + 0] = cx; c[3 * k + 1] = cy; c[3 * k + 2] = cz;
        n[3 * k + 0] = nx; n[3 * k + 1] = ny; n[3 * k + 2] = nz;
    }

    size_t ob = (size_t)p * 6;
#pragma unroll
    for (int q = 0; q < 6; ++q) {
        f32x4 v = {c[4 * q + 0], c[4 * q + 1], c[4 * q + 2], c[4 * q + 3]};
        coords[ob + q] = v;
    }
#pragma unroll
    for (int q = 0; q < 6; ++q) {
        f32x4 v = {n[4 * q + 0], n[4 * q + 1], n[4 * q + 2], n[4 * q + 3]};
        normals[ob + q] = v;
    }

    f32x4 img;
    if (fid[0] >= 0) {
        f32x4 t = *(const f32x4*)(texels + (size_t)p * (KF * 3));
        img.x = t.x; img.y = t.y; img.z = t.z; img.w = 1.0f;
    } else {
        img.x = 1.0f; img.y = 1.0f; img.z = 1.0f; img.w = 0.0f;
    }
    images[p] = img;
}

extern "C" void kernel_launch(void* const* d_in, const int* in_sizes, int n_in,
                              void* d_out, int out_size, void* d_ws, size_t ws_size,
                              hipStream_t stream) {
    const float* verts = (const float*)d_in[0];
    const int* faces = (const int*)d_in[1];
    const float* fnorm = (const float*)d_in[2];
    const int* p2f = (const int*)d_in[3];
    const float* texels = (const float*)d_in[4];

    const int F = in_sizes[1] / 3;
    const int npix = in_sizes[3] / KF;   // N*H*W

    float* out = (float*)d_out;
    f32x4* images = (f32x4*)out;
    f32x4* coords = (f32x4*)(out + (size_t)npix * 4);
    f32x4* normals = (f32x4*)(out + (size_t)npix * 4 + (size_t)npix * 24);

    const size_t ws_needed = (size_t)F * sizeof(u32x4);   // 3.2 MB

    dim3 blk(256);

    if (ws_size >= ws_needed && (npix % 256) == 0) {
        u32x4* table = (u32x4*)d_ws;
        dim3 grid_f((F + 255) / 256);
        build_face_table_kernel<<<grid_f, blk, 0, stream>>>(verts, faces, fnorm, table, F);
        dim3 grid_pix(npix / 256);
        shade_lds_kernel<<<grid_pix, blk, 0, stream>>>(p2f, texels, table,
                                                       images, coords, normals, npix);
    } else {
        dim3 grid_pix((npix + 255) / 256);
        shade_inline_kernel<<<grid_pix, blk, 0, stream>>>(p2f, texels, verts, faces, fnorm,
                                                          images, coords, normals, npix);
    }
}

// Round 6
// 147.736 us; speedup vs baseline: 1.1033x; 1.1033x over previous
//
#include <hip/hip_runtime.h>

// N=8, H=512, W=512, K=8, V=100000, F=200000.
// Outputs flat in d_out (f32): images (npix*4) | coords (npix*24) | normals (npix*24)
//
// R6:
//  - bf16 face table 16B/face (3.2 MB, per-XCD-L2-resident)           [R2]
//  - NT loads on streamed inputs (p2f, texels)                        [R3]
//  - LDS-staged, lane-consecutive f32x4 output stores                 [R4: 242->161us]
//  - NEW: NT *stores* on coords/normals/images. Safe now: every store
//    instruction covers 16 full 64B lines (R2's 2.4x amplification came from
//    96B-stride partial lines). NT keeps the 460MB write stream out of L2 so
//    the table stops being evicted -> gathers stay L2 hits.

#define KF 8
#define ROWSTRIDE 261   // f32x4 slots per 'sub' row

typedef float f32x4 __attribute__((ext_vector_type(4)));
typedef int   i32x4 __attribute__((ext_vector_type(4)));
typedef unsigned int u32x4 __attribute__((ext_vector_type(4)));

__device__ __forceinline__ unsigned short f2bf(float x) {
    unsigned u = __float_as_uint(x);
    unsigned r = u + 0x7FFFu + ((u >> 16) & 1u);   // round-to-nearest-even
    return (unsigned short)(r >> 16);
}
__device__ __forceinline__ float bf2f(unsigned int hi16) {
    return __uint_as_float(hi16 << 16);
}

// ---------------------------------------------------------------------------
// Kernel 1: bf16 face table, 16 B/face: {cx,cy | cz,nx | ny,nz | 0}
// Normal (cached) stores: we WANT the table resident.
// ---------------------------------------------------------------------------
__global__ void build_face_table_kernel(const float* __restrict__ verts,
                                        const int* __restrict__ faces,
                                        const float* __restrict__ fnorm,
                                        u32x4* __restrict__ table,
                                        int F) {
    int f = blockIdx.x * blockDim.x + threadIdx.x;
    if (f >= F) return;
    int i0 = faces[3 * f + 0];
    int i1 = faces[3 * f + 1];
    int i2 = faces[3 * f + 2];
    const float inv3 = 1.0f / 3.0f;
    float cx = (verts[3 * i0 + 0] + verts[3 * i1 + 0] + verts[3 * i2 + 0]) * inv3;
    float cy = (verts[3 * i0 + 1] + verts[3 * i1 + 1] + verts[3 * i2 + 1]) * inv3;
    float cz = (verts[3 * i0 + 2] + verts[3 * i1 + 2] + verts[3 * i2 + 2]) * inv3;
    float nx = fnorm[3 * f + 0];
    float ny = fnorm[3 * f + 1];
    float nz = fnorm[3 * f + 2];
    u32x4 t;
    t.x = (unsigned)f2bf(cx) | ((unsigned)f2bf(cy) << 16);
    t.y = (unsigned)f2bf(cz) | ((unsigned)f2bf(nx) << 16);
    t.z = (unsigned)f2bf(ny) | ((unsigned)f2bf(nz) << 16);
    t.w = 0u;
    table[f] = t;
}

// ---------------------------------------------------------------------------
// Kernel 2 (fast path, npix % 256 == 0): b128 LDS transpose + NT coalesced stores
// ---------------------------------------------------------------------------
__global__ void __launch_bounds__(256) shade_lds_kernel(
    const int* __restrict__ p2f,
    const float* __restrict__ texels,
    const u32x4* __restrict__ table,
    f32x4* __restrict__ images,    // npix
    f32x4* __restrict__ coords,    // npix*6
    f32x4* __restrict__ normals,   // npix*6
    int npix) {
    __shared__ f32x4 lds4[6 * ROWSTRIDE];
    const int tid = threadIdx.x;
    const int p = blockIdx.x * 256 + tid;   // grid sized so p < npix

    const i32x4* pf = (const i32x4*)(p2f + (size_t)p * KF);
    i32x4 fa = __builtin_nontemporal_load(&pf[0]);
    i32x4 fb = __builtin_nontemporal_load(&pf[1]);
    int fid[KF] = {fa.x, fa.y, fa.z, fa.w, fb.x, fb.y, fb.z, fb.w};

    // hoist texel load: in flight during the gathers
    bool fg = fa.x >= 0;
    f32x4 tex;
    if (fg) tex = __builtin_nontemporal_load((const f32x4*)(texels + (size_t)p * (KF * 3)));

    float c[24], n[24];
#pragma unroll
    for (int k = 0; k < KF; ++k) {
        int f = fid[k];
        int fs = f < 0 ? 0 : f;                  // predicated safe index
        u32x4 t = table[fs];                     // cached gather (L2-resident)
        bool live = f >= 0;
        c[3 * k + 0] = live ? bf2f(t.x & 0xFFFFu) : 0.0f;
        c[3 * k + 1] = live ? bf2f(t.x >> 16)     : 0.0f;
        c[3 * k + 2] = live ? bf2f(t.y & 0xFFFFu) : 0.0f;
        n[3 * k + 0] = live ? bf2f(t.y >> 16)     : 0.0f;
        n[3 * k + 1] = live ? bf2f(t.z & 0xFFFFu) : 0.0f;
        n[3 * k + 2] = live ? bf2f(t.z >> 16)     : 0.0f;
    }

    const size_t gbase = (size_t)blockIdx.x * (256 * 6);   // block's f32x4 base

    // ---- pass 1: coords ----
#pragma unroll
    for (int q = 0; q < 6; ++q) {
        f32x4 v = {c[4 * q + 0], c[4 * q + 1], c[4 * q + 2], c[4 * q + 3]};
        lds4[q * ROWSTRIDE + tid] = v;          // lane-contiguous b128 write
    }

    // images store in the barrier shadow (lane-consecutive -> full lines -> NT safe)
    f32x4 img;
    if (fg) { img.x = tex.x; img.y = tex.y; img.z = tex.z; img.w = 1.0f; }
    else    { img.x = 1.0f;  img.y = 1.0f;  img.z = 1.0f;  img.w = 0.0f; }
    __builtin_nontemporal_store(img, &images[p]);

    __syncthreads();
#pragma unroll
    for (int j = 0; j < 6; ++j) {
        int idx = tid + 256 * j;                // 0..1535 lane-consecutive
        int pix = idx / 6;
        int sub = idx - pix * 6;
        f32x4 v = lds4[sub * ROWSTRIDE + pix];
        __builtin_nontemporal_store(v, &coords[gbase + idx]);   // full-line NT store
    }
    __syncthreads();

    // ---- pass 2: normals ----
#pragma unroll
    for (int q = 0; q < 6; ++q) {
        f32x4 v = {n[4 * q + 0], n[4 * q + 1], n[4 * q + 2], n[4 * q + 3]};
        lds4[q * ROWSTRIDE + tid] = v;
    }
    __syncthreads();
#pragma unroll
    for (int j = 0; j < 6; ++j) {
        int idx = tid + 256 * j;
        int pix = idx / 6;
        int sub = idx - pix * 6;
        f32x4 v = lds4[sub * ROWSTRIDE + pix];
        __builtin_nontemporal_store(v, &normals[gbase + idx]);
    }
}

// ---------------------------------------------------------------------------
// Fallback (ws too small or npix % 256 != 0): inline gather, direct stores.
// ---------------------------------------------------------------------------
__global__ void __launch_bounds__(256) shade_inline_kernel(
    const int* __restrict__ p2f,
    const float* __restrict__ texels,
    const float* __restrict__ verts,
    const int* __restrict__ faces,
    const float* __restrict__ fnorm,
    f32x4* __restrict__ images,
    f32x4* __restrict__ coords,
    f32x4* __restrict__ normals,
    int npix) {
    int p = blockIdx.x * blockDim.x + threadIdx.x;
    if (p >= npix) return;

    const i32x4* pf = (const i32x4*)(p2f + (size_t)p * KF);
    i32x4 fa = pf[0];
    i32x4 fb = pf[1];
    int fid[KF] = {fa.x, fa.y, fa.z, fa.w, fb.x, fb.y, fb.z, fb.w};

    float c[24], n[24];
#pragma unroll
    for (int k = 0; k < KF; ++k) {
        int f = fid[k];
        float cx = 0.f, cy = 0.f, cz = 0.f, nx = 0.f, ny = 0.f, nz = 0.f;
        if (f >= 0) {
            int i0 = faces[3 * f + 0];
            int i1 = faces[3 * f + 1];
            int i2 = faces[3 * f + 2];
            const float inv3 = 1.0f / 3.0f;
            cx = (verts[3 * i0 + 0] + verts[3 * i1 + 0] + verts[3 * i2 + 0]) * inv3;
            cy = (verts[3 * i0 + 1] + verts[3 * i1 + 1] + verts[3 * i2 + 1]) * inv3;
            cz = (verts[3 * i0 + 2] + verts[3 * i1 + 2] + verts[3 * i2 + 2]) * inv3;
            nx = fnorm[3 * f + 0];
            ny = fnorm[3 * f + 1];
            nz = fnorm[3 * f + 2];
        }
        c[3 * k + 0] = cx; c[3 * k + 1] = cy; c[3 * k + 2] = cz;
        n[3 * k + 0] = nx; n[3 * k + 1] = ny; n[3 * k + 2] = nz;
    }

    size_t ob = (size_t)p * 6;
#pragma unroll
    for (int q = 0; q < 6; ++q) {
        f32x4 v = {c[4 * q + 0], c[4 * q + 1], c[4 * q + 2], c[4 * q + 3]};
        coords[ob + q] = v;
    }
#pragma unroll
    for (int q = 0; q < 6; ++q) {
        f32x4 v = {n[4 * q + 0], n[4 * q + 1], n[4 * q + 2], n[4 * q + 3]};
        normals[ob + q] = v;
    }

    f32x4 img;
    if (fid[0] >= 0) {
        f32x4 t = *(const f32x4*)(texels + (size_t)p * (KF * 3));
        img.x = t.x; img.y = t.y; img.z = t.z; img.w = 1.0f;
    } else {
        img.x = 1.0f; img.y = 1.0f; img.z = 1.0f; img.w = 0.0f;
    }
    images[p] = img;
}

extern "C" void kernel_launch(void* const* d_in, const int* in_sizes, int n_in,
                              void* d_out, int out_size, void* d_ws, size_t ws_size,
                              hipStream_t stream) {
    const float* verts = (const float*)d_in[0];
    const int* faces = (const int*)d_in[1];
    const float* fnorm = (const float*)d_in[2];
    const int* p2f = (const int*)d_in[3];
    const float* texels = (const float*)d_in[4];

    const int F = in_sizes[1] / 3;
    const int npix = in_sizes[3] / KF;   // N*H*W

    float* out = (float*)d_out;
    f32x4* images = (f32x4*)out;
    f32x4* coords = (f32x4*)(out + (size_t)npix * 4);
    f32x4* normals = (f32x4*)(out + (size_t)npix * 4 + (size_t)npix * 24);

    const size_t ws_needed = (size_t)F * sizeof(u32x4);   // 3.2 MB

    dim3 blk(256);

    if (ws_size >= ws_needed && (npix % 256) == 0) {
        u32x4* table = (u32x4*)d_ws;
        dim3 grid_f((F + 255) / 256);
        build_face_table_kernel<<<grid_f, blk, 0, stream>>>(verts, faces, fnorm, table, F);
        dim3 grid_pix(npix / 256);
        shade_lds_kernel<<<grid_pix, blk, 0, stream>>>(p2f, texels, table,
                                                       images, coords, normals, npix);
    } else {
        dim3 grid_pix((npix + 255) / 256);
        shade_inline_kernel<<<grid_pix, blk, 0, stream>>>(p2f, texels, verts, faces, fnorm,
                                                          images, coords, normals, npix);
    }
}

// Round 7
// 146.976 us; speedup vs baseline: 1.1090x; 1.0052x over previous
//
#include <hip/hip_runtime.h>

// N=8, H=512, W=512, K=8, V=100000, F=200000.
// Outputs flat in d_out (f32): images (npix*4) | coords (npix*24) | normals (npix*24)
//
// R7:
//  - bf16 face table 16B/face (3.2 MB, per-XCD-L2-resident)           [R2]
//  - NT loads on streamed inputs (p2f, texels)                        [R3]
//  - LDS-staged, lane-consecutive f32x4 output stores                 [R4: 242->161us]
//  - Full-line NT stores on all outputs                               [R6: 163->148us]
//  - NEW: exec-masked table gather: `if (f>=0) t = table[f]`. Background
//    lanes (~50%) issue NO memory request (vs predicated max(f,0) which
//    issued all 64 lanes). Halves L2 gather-request count.

#define KF 8
#define ROWSTRIDE 261   // f32x4 slots per 'sub' row

typedef float f32x4 __attribute__((ext_vector_type(4)));
typedef int   i32x4 __attribute__((ext_vector_type(4)));
typedef unsigned int u32x4 __attribute__((ext_vector_type(4)));

__device__ __forceinline__ unsigned short f2bf(float x) {
    unsigned u = __float_as_uint(x);
    unsigned r = u + 0x7FFFu + ((u >> 16) & 1u);   // round-to-nearest-even
    return (unsigned short)(r >> 16);
}
__device__ __forceinline__ float bf2f(unsigned int hi16) {
    return __uint_as_float(hi16 << 16);
}

// ---------------------------------------------------------------------------
// Kernel 1: bf16 face table, 16 B/face: {cx,cy | cz,nx | ny,nz | 0}
// Normal (cached) stores: we WANT the table resident.
// ---------------------------------------------------------------------------
__global__ void build_face_table_kernel(const float* __restrict__ verts,
                                        const int* __restrict__ faces,
                                        const float* __restrict__ fnorm,
                                        u32x4* __restrict__ table,
                                        int F) {
    int f = blockIdx.x * blockDim.x + threadIdx.x;
    if (f >= F) return;
    int i0 = faces[3 * f + 0];
    int i1 = faces[3 * f + 1];
    int i2 = faces[3 * f + 2];
    const float inv3 = 1.0f / 3.0f;
    float cx = (verts[3 * i0 + 0] + verts[3 * i1 + 0] + verts[3 * i2 + 0]) * inv3;
    float cy = (verts[3 * i0 + 1] + verts[3 * i1 + 1] + verts[3 * i2 + 1]) * inv3;
    float cz = (verts[3 * i0 + 2] + verts[3 * i1 + 2] + verts[3 * i2 + 2]) * inv3;
    float nx = fnorm[3 * f + 0];
    float ny = fnorm[3 * f + 1];
    float nz = fnorm[3 * f + 2];
    u32x4 t;
    t.x = (unsigned)f2bf(cx) | ((unsigned)f2bf(cy) << 16);
    t.y = (unsigned)f2bf(cz) | ((unsigned)f2bf(nx) << 16);
    t.z = (unsigned)f2bf(ny) | ((unsigned)f2bf(nz) << 16);
    t.w = 0u;
    table[f] = t;
}

// ---------------------------------------------------------------------------
// Kernel 2 (fast path, npix % 256 == 0): masked gather + b128 LDS transpose
//                                        + full-line NT stores
// ---------------------------------------------------------------------------
__global__ void __launch_bounds__(256) shade_lds_kernel(
    const int* __restrict__ p2f,
    const float* __restrict__ texels,
    const u32x4* __restrict__ table,
    f32x4* __restrict__ images,    // npix
    f32x4* __restrict__ coords,    // npix*6
    f32x4* __restrict__ normals,   // npix*6
    int npix) {
    __shared__ f32x4 lds4[6 * ROWSTRIDE];
    const int tid = threadIdx.x;
    const int p = blockIdx.x * 256 + tid;   // grid sized so p < npix

    const i32x4* pf = (const i32x4*)(p2f + (size_t)p * KF);
    i32x4 fa = __builtin_nontemporal_load(&pf[0]);
    i32x4 fb = __builtin_nontemporal_load(&pf[1]);
    int fid[KF] = {fa.x, fa.y, fa.z, fa.w, fb.x, fb.y, fb.z, fb.w};

    // hoist texel load: in flight during the gathers (exec-masked already)
    bool fg = fa.x >= 0;
    f32x4 tex;
    if (fg) tex = __builtin_nontemporal_load((const f32x4*)(texels + (size_t)p * (KF * 3)));

    float c[24], n[24];
#pragma unroll
    for (int k = 0; k < KF; ++k) {
        int f = fid[k];
        u32x4 t = {0u, 0u, 0u, 0u};
        if (f >= 0) t = table[f];     // exec-masked: bg lanes issue NO request
        c[3 * k + 0] = bf2f(t.x & 0xFFFFu);
        c[3 * k + 1] = bf2f(t.x >> 16);
        c[3 * k + 2] = bf2f(t.y & 0xFFFFu);
        n[3 * k + 0] = bf2f(t.y >> 16);
        n[3 * k + 1] = bf2f(t.z & 0xFFFFu);
        n[3 * k + 2] = bf2f(t.z >> 16);
    }

    const size_t gbase = (size_t)blockIdx.x * (256 * 6);   // block's f32x4 base

    // ---- pass 1: coords ----
#pragma unroll
    for (int q = 0; q < 6; ++q) {
        f32x4 v = {c[4 * q + 0], c[4 * q + 1], c[4 * q + 2], c[4 * q + 3]};
        lds4[q * ROWSTRIDE + tid] = v;          // lane-contiguous b128 write
    }

    // images store in the barrier shadow (lane-consecutive -> full lines -> NT safe)
    f32x4 img;
    if (fg) { img.x = tex.x; img.y = tex.y; img.z = tex.z; img.w = 1.0f; }
    else    { img.x = 1.0f;  img.y = 1.0f;  img.z = 1.0f;  img.w = 0.0f; }
    __builtin_nontemporal_store(img, &images[p]);

    __syncthreads();
#pragma unroll
    for (int j = 0; j < 6; ++j) {
        int idx = tid + 256 * j;                // 0..1535 lane-consecutive
        int pix = idx / 6;
        int sub = idx - pix * 6;
        f32x4 v = lds4[sub * ROWSTRIDE + pix];
        __builtin_nontemporal_store(v, &coords[gbase + idx]);   // full-line NT store
    }
    __syncthreads();

    // ---- pass 2: normals ----
#pragma unroll
    for (int q = 0; q < 6; ++q) {
        f32x4 v = {n[4 * q + 0], n[4 * q + 1], n[4 * q + 2], n[4 * q + 3]};
        lds4[q * ROWSTRIDE + tid] = v;
    }
    __syncthreads();
#pragma unroll
    for (int j = 0; j < 6; ++j) {
        int idx = tid + 256 * j;
        int pix = idx / 6;
        int sub = idx - pix * 6;
        f32x4 v = lds4[sub * ROWSTRIDE + pix];
        __builtin_nontemporal_store(v, &normals[gbase + idx]);
    }
}

// ---------------------------------------------------------------------------
// Fallback (ws too small or npix % 256 != 0): inline gather, direct stores.
// ---------------------------------------------------------------------------
__global__ void __launch_bounds__(256) shade_inline_kernel(
    const int* __restrict__ p2f,
    const float* __restrict__ texels,
    const float* __restrict__ verts,
    const int* __restrict__ faces,
    const float* __restrict__ fnorm,
    f32x4* __restrict__ images,
    f32x4* __restrict__ coords,
    f32x4* __restrict__ normals,
    int npix) {
    int p = blockIdx.x * blockDim.x + threadIdx.x;
    if (p >= npix) return;

    const i32x4* pf = (const i32x4*)(p2f + (size_t)p * KF);
    i32x4 fa = pf[0];
    i32x4 fb = pf[1];
    int fid[KF] = {fa.x, fa.y, fa.z, fa.w, fb.x, fb.y, fb.z, fb.w};

    float c[24], n[24];
#pragma unroll
    for (int k = 0; k < KF; ++k) {
        int f = fid[k];
        float cx = 0.f, cy = 0.f, cz = 0.f, nx = 0.f, ny = 0.f, nz = 0.f;
        if (f >= 0) {
            int i0 = faces[3 * f + 0];
            int i1 = faces[3 * f + 1];
            int i2 = faces[3 * f + 2];
            const float inv3 = 1.0f / 3.0f;
            cx = (verts[3 * i0 + 0] + verts[3 * i1 + 0] + verts[3 * i2 + 0]) * inv3;
            cy = (verts[3 * i0 + 1] + verts[3 * i1 + 1] + verts[3 * i2 + 1]) * inv3;
            cz = (verts[3 * i0 + 2] + verts[3 * i1 + 2] + verts[3 * i2 + 2]) * inv3;
            nx = fnorm[3 * f + 0];
            ny = fnorm[3 * f + 1];
            nz = fnorm[3 * f + 2];
        }
        c[3 * k + 0] = cx; c[3 * k + 1] = cy; c[3 * k + 2] = cz;
        n[3 * k + 0] = nx; n[3 * k + 1] = ny; n[3 * k + 2] = nz;
    }

    size_t ob = (size_t)p * 6;
#pragma unroll
    for (int q = 0; q < 6; ++q) {
        f32x4 v = {c[4 * q + 0], c[4 * q + 1], c[4 * q + 2], c[4 * q + 3]};
        coords[ob + q] = v;
    }
#pragma unroll
    for (int q = 0; q < 6; ++q) {
        f32x4 v = {n[4 * q + 0], n[4 * q + 1], n[4 * q + 2], n[4 * q + 3]};
        normals[ob + q] = v;
    }

    f32x4 img;
    if (fid[0] >= 0) {
        f32x4 t = *(const f32x4*)(texels + (size_t)p * (KF * 3));
        img.x = t.x; img.y = t.y; img.z = t.z; img.w = 1.0f;
    } else {
        img.x = 1.0f; img.y = 1.0f; img.z = 1.0f; img.w = 0.0f;
    }
    images[p] = img;
}

extern "C" void kernel_launch(void* const* d_in, const int* in_sizes, int n_in,
                              void* d_out, int out_size, void* d_ws, size_t ws_size,
                              hipStream_t stream) {
    const float* verts = (const float*)d_in[0];
    const int* faces = (const int*)d_in[1];
    const float* fnorm = (const float*)d_in[2];
    const int* p2f = (const int*)d_in[3];
    const float* texels = (const float*)d_in[4];

    const int F = in_sizes[1] / 3;
    const int npix = in_sizes[3] / KF;   // N*H*W

    float* out = (float*)d_out;
    f32x4* images = (f32x4*)out;
    f32x4* coords = (f32x4*)(out + (size_t)npix * 4);
    f32x4* normals = (f32x4*)(out + (size_t)npix * 4 + (size_t)npix * 24);

    const size_t ws_needed = (size_t)F * sizeof(u32x4);   // 3.2 MB

    dim3 blk(256);

    if (ws_size >= ws_needed && (npix % 256) == 0) {
        u32x4* table = (u32x4*)d_ws;
        dim3 grid_f((F + 255) / 256);
        build_face_table_kernel<<<grid_f, blk, 0, stream>>>(verts, faces, fnorm, table, F);
        dim3 grid_pix(npix / 256);
        shade_lds_kernel<<<grid_pix, blk, 0, stream>>>(p2f, texels, table,
                                                       images, coords, normals, npix);
    } else {
        dim3 grid_pix((npix + 255) / 256);
        shade_inline_kernel<<<grid_pix, blk, 0, stream>>>(p2f, texels, verts, faces, fnorm,
                                                          images, coords, normals, npix);
    }
}